// Round 13
// baseline (2143.829 us; speedup 1.0000x reference)
//
#include <hip/hip_runtime.h>

typedef _Float16 f16;
typedef __attribute__((ext_vector_type(8))) _Float16 f16x8;
typedef __attribute__((ext_vector_type(4))) _Float16 f16x4;
typedef __attribute__((ext_vector_type(4))) float f32x4;
typedef __attribute__((ext_vector_type(16))) float f32x16;
typedef __attribute__((ext_vector_type(4))) unsigned u32x4;

#define T_SEQ 2048
#define NBATCH 4

__device__ __forceinline__ void gld_lds16(const f16* g, f16* l) {
    __builtin_amdgcn_global_load_lds((const __attribute__((address_space(1))) void*)g,
                                     (__attribute__((address_space(3))) void*)l, 16, 0, 0);
}

__device__ __forceinline__ unsigned pk2(float a, float b) {
    __attribute__((ext_vector_type(2))) __fp16 h = __builtin_amdgcn_cvt_pkrtz(a, b);
    return __builtin_bit_cast(unsigned, h);
}

// ---------- fused prep: cast x | transpose Wq/Wk/Wv/Wo | xPos tables ----------
__global__ __launch_bounds__(256) void k_prep(const float* __restrict__ x,
                                              const float* __restrict__ Wq,
                                              const float* __restrict__ Wk,
                                              const float* __restrict__ Wv,
                                              const float* __restrict__ Wo,
                                              f16* __restrict__ xh,
                                              f16* __restrict__ wqkvT,
                                              f16* __restrict__ woT,
                                              float* __restrict__ tab) {
    __shared__ float tile[32][33];
    int bidx = blockIdx.x;
    if (bidx < 16384) {  // cast x fp32 -> fp16 (float4 per thread)
        int i = bidx * 256 + threadIdx.x;
        float4 v = ((const float4*)x)[i];
        f16x4 o = { (f16)v.x, (f16)v.y, (f16)v.z, (f16)v.w };
        ((f16x4*)xh)[i] = o;
        return;
    }
    bidx -= 16384;
    if (bidx >= 12288) {  // tables: cos | sin | scale, each [T][64] fp32
        int i = (bidx - 12288) * 256 + threadIdx.x;  // 131072 total
        int t = i >> 6, f = i & 63;
        float inv_freq = powf(10000.0f, -(2.0f * f) / 128.0f);
        float ang = (float)t * inv_freq;
        float sv = (2.0f * f + 51.2f) / 179.2f;
        float pw = ((float)t - 1024.0f) / 512.0f;
        tab[i] = cosf(ang);
        tab[131072 + i] = sinf(ang);
        tab[262144 + i] = powf(sv, pw);
        return;
    }
    // weight transpose+cast: dst[n][k] = (f16)src[k][n], K=2048
    const float* src; f16* dst; int N, bx, by;
    if (bidx < 4096)      { src = Wq; dst = wqkvT;                      N = 2048; bx = bidx & 63; by = bidx >> 6; }
    else if (bidx < 6144) { src = Wk; dst = wqkvT + (size_t)2048 * 2048; N = 1024; int t2 = bidx - 4096; bx = t2 & 31; by = t2 >> 5; }
    else if (bidx < 8192) { src = Wv; dst = wqkvT + (size_t)3072 * 2048; N = 1024; int t2 = bidx - 6144; bx = t2 & 31; by = t2 >> 5; }
    else                  { src = Wo; dst = woT;                        N = 2048; int t2 = bidx - 8192; bx = t2 & 63; by = t2 >> 6; }
    int n0 = bx * 32, k0 = by * 32;
    int tx = threadIdx.x & 31, ty = threadIdx.x >> 5;  // 32 x 8
#pragma unroll
    for (int j = 0; j < 32; j += 8)
        tile[ty + j][tx] = src[(size_t)(k0 + ty + j) * N + n0 + tx];
    __syncthreads();
#pragma unroll
    for (int j = 0; j < 32; j += 8)
        dst[(size_t)(n0 + ty + j) * 2048 + k0 + tx] = (f16)tile[tx][ty + j];
}

// ---------- V blocked-transpose for attention ----------
__global__ __launch_bounds__(256) void k_vtrans(const f16* __restrict__ qkv, f16* __restrict__ vtg) {
    const int kt = blockIdx.x, bk = blockIdx.y;
    const int b = bk >> 3, kvh = bk & 7;
    const int tid = threadIdx.x;
    __shared__ f16 tile[64][132];
#pragma unroll
    for (int p = 0; p < 4; ++p) {
        int idx = p * 256 + tid;
        int r = idx >> 4, dc = (idx & 15) * 8;
        f16x8 v = *(const f16x8*)(qkv + (size_t)(b * T_SEQ + kt * 64 + r) * 4096 + 3072 + kvh * 128 + dc);
#pragma unroll
        for (int j = 0; j < 8; ++j) tile[r][dc + j] = v[j];
    }
    __syncthreads();
    f16* outb = vtg + (size_t)(bk * 32 + kt) * 8192;
#pragma unroll
    for (int p = 0; p < 4; ++p) {
        int c = p * 256 + tid;
        int kchunk = c >> 7, d = c & 127;
        f16x8 o;
#pragma unroll
        for (int j = 0; j < 8; ++j) o[j] = tile[kchunk * 8 + j][d];
        *(f16x8*)(outb + (size_t)c * 8) = o;
    }
}

// ---------- 256x256 GEMM, BK=32, 2 blocks/CU (64 KB LDS) ----------
// Stage unit u = (w*2+r)*64 + lane -> LDS dest base (w*2+r)*64*16B is WAVE-UNIFORM
// (global_load_lds places lane i at base+i*16B; per-lane dest bases are invalid).
// Swizzle: LDS slot cc of row holds global chunk cc^((row>>1)&3); read slot
// gq^((R>>1)&3) returns chunk gq. 2 blocks/CU = 4 waves/SIMD for TLP bubble-cover.
template <typename OutT>
__global__ __launch_bounds__(512, 4) void k_gemm256(const f16* __restrict__ A,
                                                    const f16* __restrict__ B,
                                                    OutT* __restrict__ C, int M, int N, int K) {
    extern __shared__ char smem[];
    f16* As = (f16*)smem;            // [2][256][32]
    f16* Bs = (f16*)smem + 16384;    // [2][256][32]
    const int tid = threadIdx.x, lane = tid & 63, w = tid >> 6;
    const int wr4 = w >> 1, wc2 = w & 1;
    const int cq = lane & 15, gq = lane >> 4;
    const int nbx = gridDim.x;                 // n tiles: 16 (GEMM1) or 8 (GEMM2)
    const int bid0 = blockIdx.y * nbx + blockIdx.x;
    const int x = bid0 & 7, idx = bid0 >> 3;   // XCD id, local index
    const int snb = (nbx == 16) ? 3 : 2;       // log2(nbx/2)
    const int mt = (x >> 1) * 8 + (idx >> snb);
    const int nt = (x & 1) * (nbx >> 1) + (idx & ((nbx >> 1) - 1));
    const int m0 = mt * 256, n0 = nt * 256;
    const int KT = K >> 5;

    f32x4 acc[2][2][2][4] = {};
    f16x8 aL[2], aH[2], bL[4], bH[4];

    // stage one K-tile (256 rows x 32 k) of A and B; per-(wave,r) base is uniform
    auto stage = [&](int buf, int t) {
#pragma unroll
        for (int r = 0; r < 2; ++r) {
            int ub = (w * 2 + r) * 64;        // wave-uniform base unit
            int u = ub + lane;
            int row = u >> 2, cc = u & 3;
            int sc = cc ^ ((row >> 1) & 3);
            gld_lds16(A + (size_t)(m0 + row) * K + t * 32 + sc * 8,
                      As + buf * 8192 + ub * 8);
            gld_lds16(B + (size_t)(n0 + row) * K + t * 32 + sc * 8,
                      Bs + buf * 8192 + ub * 8);
        }
    };
    auto rdA = [&](int buf, int qr, f16x8 a[2]) {
#pragma unroll
        for (int mi = 0; mi < 2; ++mi) {
            int R = qr * 128 + wr4 * 32 + mi * 16 + cq;
            a[mi] = *(const f16x8*)&As[buf * 8192 + R * 32 + ((gq ^ ((R >> 1) & 3)) * 8)];
        }
    };
    auto rdB = [&](int buf, int qc, f16x8 b[4]) {
#pragma unroll
        for (int ni = 0; ni < 4; ++ni) {
            int R = qc * 128 + wc2 * 64 + ni * 16 + cq;
            b[ni] = *(const f16x8*)&Bs[buf * 8192 + R * 32 + ((gq ^ ((R >> 1) & 3)) * 8)];
        }
    };

    stage(0, 0);

#pragma unroll 1
    for (int t = 0; t < KT; ++t) {
        const int buf = t & 1;
        if (t + 1 < KT) {
            stage(buf ^ 1, t + 1);
            asm volatile("s_waitcnt vmcnt(4)");   // tile t landed; t+1 in flight
        } else {
            asm volatile("s_waitcnt vmcnt(0)");
        }
        __builtin_amdgcn_s_barrier();             // buf(t) ready for all waves

        rdA(buf, 0, aL); rdB(buf, 0, bL); rdB(buf, 1, bH); rdA(buf, 1, aH);
        __builtin_amdgcn_s_setprio(1);
#pragma unroll
        for (int mi = 0; mi < 2; ++mi)
#pragma unroll
            for (int ni = 0; ni < 4; ++ni)
                acc[0][0][mi][ni] = __builtin_amdgcn_mfma_f32_16x16x32_f16(aL[mi], bL[ni], acc[0][0][mi][ni], 0, 0, 0);
#pragma unroll
        for (int mi = 0; mi < 2; ++mi)
#pragma unroll
            for (int ni = 0; ni < 4; ++ni)
                acc[0][1][mi][ni] = __builtin_amdgcn_mfma_f32_16x16x32_f16(aL[mi], bH[ni], acc[0][1][mi][ni], 0, 0, 0);
#pragma unroll
        for (int mi = 0; mi < 2; ++mi)
#pragma unroll
            for (int ni = 0; ni < 4; ++ni)
                acc[1][1][mi][ni] = __builtin_amdgcn_mfma_f32_16x16x32_f16(aH[mi], bH[ni], acc[1][1][mi][ni], 0, 0, 0);
#pragma unroll
        for (int mi = 0; mi < 2; ++mi)
#pragma unroll
            for (int ni = 0; ni < 4; ++ni)
                acc[1][0][mi][ni] = __builtin_amdgcn_mfma_f32_16x16x32_f16(aH[mi], bL[ni], acc[1][0][mi][ni], 0, 0, 0);
        __builtin_amdgcn_s_setprio(0);
        __builtin_amdgcn_s_barrier();             // all reads of buf(t) done; next stage may overwrite
    }

#pragma unroll
    for (int qr = 0; qr < 2; ++qr)
#pragma unroll
        for (int qc = 0; qc < 2; ++qc)
#pragma unroll
            for (int mi = 0; mi < 2; ++mi)
#pragma unroll
                for (int ni = 0; ni < 4; ++ni)
#pragma unroll
                    for (int i = 0; i < 4; ++i) {
                        int row = m0 + qr * 128 + wr4 * 32 + mi * 16 + gq * 4 + i;
                        int col = n0 + qc * 128 + wc2 * 64 + ni * 16 + cq;
                        C[(size_t)row * N + col] = (OutT)acc[qr][qc][mi][ni][i];
                    }
}

// ---------- in-place xPos RoPE on qkv [8192][4096]; Q gets *scale*rsqrt(d), K gets /scale ----------
__global__ __launch_bounds__(256) void k_rope(f16* __restrict__ qkv, const float* __restrict__ tab) {
    int idx = blockIdx.x * 256 + threadIdx.x;
    const int QTOT = NBATCH * T_SEQ * 16 * 64;  // 8,388,608
    int f, col0, bt;
    bool isQ = idx < QTOT;
    if (isQ) {
        f = idx & 63; int hh = (idx >> 6) & 15; bt = idx >> 10;
        col0 = hh * 128 + f;
    } else {
        int j = idx - QTOT;
        f = j & 63; int hh = (j >> 6) & 7; bt = j >> 9;
        col0 = 2048 + hh * 128 + f;
    }
    int t = bt & (T_SEQ - 1);
    float cs = tab[t * 64 + f], sn = tab[131072 + t * 64 + f], sc = tab[262144 + t * 64 + f];
    float mult = isQ ? sc * 0.08838834764831845f : 1.0f / sc;  // fold 1/sqrt(128) into Q
    size_t p = (size_t)bt * 4096 + col0;
    float x1 = (float)qkv[p], x2 = (float)qkv[p + 64];
    qkv[p]      = (f16)((x1 * cs - x2 * sn) * mult);
    qkv[p + 64] = (f16)((x2 * cs + x1 * sn) * mult);
}

// ---------- causal GQA flash attention, v6: triple-buffered K/V ring, counted vmcnt ----------
__global__ __launch_bounds__(512) void k_attn(const f16* __restrict__ qkv,
                                              const f16* __restrict__ vtg,
                                              f16* __restrict__ ao) {
    extern __shared__ f16 asmem[];   // [3][16384]: per buf K 8192 | V 8192
    const int bid0 = blockIdx.x;
    const int bid = (bid0 & 7) * 32 + (bid0 >> 3);  // XCD swizzle (256 = 8x32)
    const int pr = bid & 7, kvh = (bid >> 3) & 7, b = bid >> 6;
    const int bk = b * 8 + kvh;
    const int tid = threadIdx.x, lane = tid & 63, w = tid >> 6;
    const int w4 = w & 3, hg = w >> 2;
    const int h = kvh * 2 + hg;
    const int l31 = lane & 31, hi = lane >> 5;

    const f16* kbase = qkv + (size_t)b * T_SEQ * 4096 + 2048 + kvh * 128;
    const f16* vbase = vtg + (size_t)bk * 32 * 8192;

    auto stage = [&](int buf, int kt) {
        f16* kb_ = asmem + buf * 16384;
        f16* vb_ = kb_ + 8192;
#pragma unroll
        for (int qq = 0; qq < 2; ++qq) {
            int c = w * 128 + qq * 64 + lane;
            int row = c >> 4;
            int ch = (c & 15) ^ (row & 15);
            gld_lds16(kbase + (size_t)(kt * 64 + row) * 4096 + ch * 8, kb_ + (w * 128 + qq * 64) * 8);
        }
#pragma unroll
        for (int qq = 0; qq < 2; ++qq) {
            int c = w * 128 + qq * 64 + lane;
            gld_lds16(vbase + ((size_t)kt * 1024 + c) * 8, vb_ + (w * 128 + qq * 64) * 8);
        }
    };

#pragma unroll 1
    for (int hf = 0; hf < 2; ++hf) {
        const int qt = hf ? pr : (15 - pr);
        const int q0 = qt * 128;
        const int nkt = 2 * qt + 2;  // even, >= 2
        const int qrow = q0 + w4 * 32 + l31;

        f16x8 qf[8];
#pragma unroll
        for (int ds = 0; ds < 8; ++ds)
            qf[ds] = *(const f16x8*)(qkv + (size_t)(b * T_SEQ + qrow) * 4096 + h * 128 + ds * 16 + hi * 8);

        f32x16 Ot[4] = {};
        float mrow = -1e30f, lrow = 0.0f;

        stage(0, 0);
        if (nkt > 1) stage(1, 1);

#pragma unroll 1
        for (int kt = 0; kt < nkt; ++kt) {
            const int kb = kt % 3;
            const f16* Kl = asmem + kb * 16384;
            const f16* Vl = Kl + 8192;
            // wait for THIS tile's loads only; kt+1's 4 loads stay in flight
            if (kt + 1 < nkt) asm volatile("s_waitcnt vmcnt(4)");
            else              asm volatile("s_waitcnt vmcnt(0)");
            __builtin_amdgcn_s_barrier();

            if (!(kt == 2 * qt + 1 && w4 < 2)) {
                // ---- St = K Q^T (swapped): lane q = l31, k rows in regs ----
                f32x16 St0 = {}, St1 = {};
                __builtin_amdgcn_s_setprio(1);
#pragma unroll
                for (int ds = 0; ds < 8; ++ds) {
                    int slot = (((2 * ds + hi) ^ (l31 & 15)) << 3);
                    f16x8 k0 = *(const f16x8*)&Kl[l31 * 128 + slot];
                    f16x8 k1 = *(const f16x8*)&Kl[(32 + l31) * 128 + slot];
                    St0 = __builtin_amdgcn_mfma_f32_32x32x16_f16(k0, qf[ds], St0, 0, 0, 0);
                    St1 = __builtin_amdgcn_mfma_f32_32x32x16_f16(k1, qf[ds], St1, 0, 0, 0);
                }
                __builtin_amdgcn_s_setprio(0);

                // ---- causal mask ----
                if (kt >= 2 * qt) {
                    int kbase2 = kt * 64;
#pragma unroll
                    for (int r = 0; r < 16; ++r) {
                        int krel = (r & 3) + 8 * (r >> 2) + 4 * hi;
                        if (kbase2 + krel > qrow) St0[r] = -1e30f;
                        if (kbase2 + 32 + krel > qrow) St1[r] = -1e30f;
                    }
                }

                // ---- in-register online softmax ----
                float tm[16];
#pragma unroll
                for (int r = 0; r < 16; ++r) tm[r] = fmaxf(St0[r], St1[r]);
#pragma unroll
                for (int d = 8; d >= 1; d >>= 1)
#pragma unroll
                    for (int r = 0; r < 8; ++r)
                        if (r < d) tm[r] = fmaxf(tm[r], tm[r + d]);
                float tmax = tm[0];
                float mtile = fmaxf(tmax, __shfl_xor(tmax, 32, 64));

                if (!__all((mtile - mrow) <= 8.0f)) {  // T13 defer-max
                    float mnew = fmaxf(mrow, mtile);
                    float fs = __expf(mrow - mnew);
                    mrow = mnew;
                    lrow *= fs;
#pragma unroll
                    for (int dblk = 0; dblk < 4; ++dblk)
#pragma unroll
                        for (int e = 0; e < 16; ++e) Ot[dblk][e] *= fs;
                }
#pragma unroll
                for (int r = 0; r < 16; ++r) {
                    St0[r] = __expf(St0[r] - mrow);
                    St1[r] = __expf(St1[r] - mrow);
                }
                float ts[16];
#pragma unroll
                for (int r = 0; r < 16; ++r) ts[r] = St0[r] + St1[r];
#pragma unroll
                for (int d = 8; d >= 1; d >>= 1)
#pragma unroll
                    for (int r = 0; r < 8; ++r)
                        if (r < d) ts[r] += ts[r + d];
                float tsum = ts[0];
                lrow += tsum + __shfl_xor(tsum, 32, 64);

                // ---- pack P (cvt_pkrtz + shfl_xor 32) + PV ----
#define PV_P(o, pos) ((o) < 4 ? St0[((o) & 3) * 4 + (pos)] : St1[((o) & 3) * 4 + (pos)])
#pragma unroll
                for (int s = 0; s < 4; ++s) {
                    unsigned x1 = pk2(PV_P(2 * s, 0), PV_P(2 * s, 1));
                    unsigned x2 = pk2(PV_P(2 * s, 2), PV_P(2 * s, 3));
                    unsigned y1 = pk2(PV_P(2 * s + 1, 0), PV_P(2 * s + 1, 1));
                    unsigned y2 = pk2(PV_P(2 * s + 1, 2), PV_P(2 * s + 1, 3));
                    unsigned sx1 = __shfl_xor(x1, 32, 64);
                    unsigned sx2 = __shfl_xor(x2, 32, 64);
                    unsigned sy1 = __shfl_xor(y1, 32, 64);
                    unsigned sy2 = __shfl_xor(y2, 32, 64);
                    u32x4 pw;
                    pw[0] = hi ? sy1 : x1;
                    pw[1] = hi ? sy2 : x2;
                    pw[2] = hi ? y1 : sx1;
                    pw[3] = hi ? y2 : sx2;
                    f16x8 pa = __builtin_bit_cast(f16x8, pw);
                    __builtin_amdgcn_s_setprio(1);
#pragma unroll
                    for (int dblk = 0; dblk < 4; ++dblk) {
                        f16x8 vb = *(const f16x8*)&Vl[(((2 * s + hi) << 7) + 32 * dblk + l31) << 3];
                        Ot[dblk] = __builtin_amdgcn_mfma_f32_32x32x16_f16(vb, pa, Ot[dblk], 0, 0, 0);
                    }
                    __builtin_amdgcn_s_setprio(0);
                }
#undef PV_P
            }
            __builtin_amdgcn_s_barrier();  // all reads of buf kb done before its next writer issues
            if (kt + 2 < nkt) stage((kt + 2) % 3, kt + 2);
        }

        // ---- epilogue ----
        {
            float inv = 1.0f / lrow;
            size_t rowb = (size_t)(b * T_SEQ + qrow) * 2048 + h * 128;
#pragma unroll
            for (int dblk = 0; dblk < 4; ++dblk)
#pragma unroll
                for (int rg = 0; rg < 4; ++rg) {
                    f16x4 o4 = { (f16)(Ot[dblk][rg * 4 + 0] * inv), (f16)(Ot[dblk][rg * 4 + 1] * inv),
                                 (f16)(Ot[dblk][rg * 4 + 2] * inv), (f16)(Ot[dblk][rg * 4 + 3] * inv) };
                    *(f16x4*)(ao + rowb + dblk * 32 + rg * 8 + hi * 4) = o4;
                }
        }
    }
}

extern "C" void kernel_launch(void* const* d_in, const int* in_sizes, int n_in,
                              void* d_out, int out_size, void* d_ws, size_t ws_size,
                              hipStream_t stream) {
    const float* x  = (const float*)d_in[0];
    const float* Wq = (const float*)d_in[1];
    const float* Wk = (const float*)d_in[2];
    const float* Wv = (const float*)d_in[3];
    const float* Wo = (const float*)d_in[4];
    float* out = (float*)d_out;

    // workspace (fp16 elems): xh 16.7M | wqkvT 8.4M | woT 4.2M | qkv 33.5M | tab (f32)
    f16* xh    = (f16*)d_ws;
    f16* wqkvT = xh + (size_t)16777216;
    f16* woT   = wqkvT + (size_t)8388608;
    f16* qkv   = woT + (size_t)4194304;
    float* tab = (float*)(qkv + (size_t)33554432);
    f16* ao  = xh;     // alias: xh dead after GEMM1
    f16* vtg = wqkvT;  // alias: wqkvT dead after GEMM1 (8.4M f16 = exact fit)

    hipFuncSetAttribute(reinterpret_cast<const void*>(&k_gemm256<f16>),
                        hipFuncAttributeMaxDynamicSharedMemorySize, 65536);
    hipFuncSetAttribute(reinterpret_cast<const void*>(&k_gemm256<float>),
                        hipFuncAttributeMaxDynamicSharedMemorySize, 65536);
    hipFuncSetAttribute(reinterpret_cast<const void*>(&k_attn),
                        hipFuncAttributeMaxDynamicSharedMemorySize, 98304);

    k_prep<<<29184, 256, 0, stream>>>(x, Wq, Wk, Wv, Wo, xh, wqkvT, woT, tab);
    // QKV projection: qkv[8192][4096]
    k_gemm256<f16><<<dim3(16, 32), 512, 65536, stream>>>(xh, wqkvT, qkv, 8192, 4096, 2048);
    k_vtrans<<<dim3(32, 32), 256, 0, stream>>>(qkv, vtg);
    k_rope<<<49152, 256, 0, stream>>>(qkv, tab);
    k_attn<<<256, 512, 98304, stream>>>(qkv, vtg, ao);
    // output projection -> fp32
    k_gemm256<float><<<dim3(8, 32), 512, 65536, stream>>>(ao, woT, out, 8192, 2048, 2048);
}

// Round 14
// 396.882 us; speedup vs baseline: 5.4017x; 5.4017x over previous
//
#include <hip/hip_runtime.h>

typedef _Float16 f16;
typedef __attribute__((ext_vector_type(8))) _Float16 f16x8;
typedef __attribute__((ext_vector_type(4))) _Float16 f16x4;
typedef __attribute__((ext_vector_type(4))) float f32x4;
typedef __attribute__((ext_vector_type(16))) float f32x16;
typedef __attribute__((ext_vector_type(4))) unsigned u32x4;

#define T_SEQ 2048
#define NBATCH 4

__device__ __forceinline__ void gld_lds16(const f16* g, f16* l) {
    __builtin_amdgcn_global_load_lds((const __attribute__((address_space(1))) void*)g,
                                     (__attribute__((address_space(3))) void*)l, 16, 0, 0);
}

__device__ __forceinline__ unsigned pk2(float a, float b) {
    __attribute__((ext_vector_type(2))) __fp16 h = __builtin_amdgcn_cvt_pkrtz(a, b);
    return __builtin_bit_cast(unsigned, h);
}

// ---------- fused prep: cast x | transpose Wq/Wk/Wv/Wo | xPos tables ----------
__global__ __launch_bounds__(256) void k_prep(const float* __restrict__ x,
                                              const float* __restrict__ Wq,
                                              const float* __restrict__ Wk,
                                              const float* __restrict__ Wv,
                                              const float* __restrict__ Wo,
                                              f16* __restrict__ xh,
                                              f16* __restrict__ wqkvT,
                                              f16* __restrict__ woT,
                                              float* __restrict__ tab) {
    __shared__ float tile[32][33];
    int bidx = blockIdx.x;
    if (bidx < 16384) {  // cast x fp32 -> fp16 (float4 per thread)
        int i = bidx * 256 + threadIdx.x;
        float4 v = ((const float4*)x)[i];
        f16x4 o = { (f16)v.x, (f16)v.y, (f16)v.z, (f16)v.w };
        ((f16x4*)xh)[i] = o;
        return;
    }
    bidx -= 16384;
    if (bidx >= 12288) {  // tables: cos | sin | scale, each [T][64] fp32
        int i = (bidx - 12288) * 256 + threadIdx.x;  // 131072 total
        int t = i >> 6, f = i & 63;
        float inv_freq = powf(10000.0f, -(2.0f * f) / 128.0f);
        float ang = (float)t * inv_freq;
        float sv = (2.0f * f + 51.2f) / 179.2f;
        float pw = ((float)t - 1024.0f) / 512.0f;
        tab[i] = cosf(ang);
        tab[131072 + i] = sinf(ang);
        tab[262144 + i] = powf(sv, pw);
        return;
    }
    // weight transpose+cast: dst[n][k] = (f16)src[k][n], K=2048
    const float* src; f16* dst; int N, bx, by;
    if (bidx < 4096)      { src = Wq; dst = wqkvT;                      N = 2048; bx = bidx & 63; by = bidx >> 6; }
    else if (bidx < 6144) { src = Wk; dst = wqkvT + (size_t)2048 * 2048; N = 1024; int t2 = bidx - 4096; bx = t2 & 31; by = t2 >> 5; }
    else if (bidx < 8192) { src = Wv; dst = wqkvT + (size_t)3072 * 2048; N = 1024; int t2 = bidx - 6144; bx = t2 & 31; by = t2 >> 5; }
    else                  { src = Wo; dst = woT;                        N = 2048; int t2 = bidx - 8192; bx = t2 & 63; by = t2 >> 6; }
    int n0 = bx * 32, k0 = by * 32;
    int tx = threadIdx.x & 31, ty = threadIdx.x >> 5;  // 32 x 8
#pragma unroll
    for (int j = 0; j < 32; j += 8)
        tile[ty + j][tx] = src[(size_t)(k0 + ty + j) * N + n0 + tx];
    __syncthreads();
#pragma unroll
    for (int j = 0; j < 32; j += 8)
        dst[(size_t)(n0 + ty + j) * 2048 + k0 + tx] = (f16)tile[tx][ty + j];
}

// ---------- V blocked-transpose for attention ----------
__global__ __launch_bounds__(256) void k_vtrans(const f16* __restrict__ qkv, f16* __restrict__ vtg) {
    const int kt = blockIdx.x, bk = blockIdx.y;
    const int b = bk >> 3, kvh = bk & 7;
    const int tid = threadIdx.x;
    __shared__ f16 tile[64][132];
#pragma unroll
    for (int p = 0; p < 4; ++p) {
        int idx = p * 256 + tid;
        int r = idx >> 4, dc = (idx & 15) * 8;
        f16x8 v = *(const f16x8*)(qkv + (size_t)(b * T_SEQ + kt * 64 + r) * 4096 + 3072 + kvh * 128 + dc);
#pragma unroll
        for (int j = 0; j < 8; ++j) tile[r][dc + j] = v[j];
    }
    __syncthreads();
    f16* outb = vtg + (size_t)(bk * 32 + kt) * 8192;
#pragma unroll
    for (int p = 0; p < 4; ++p) {
        int c = p * 256 + tid;
        int kchunk = c >> 7, d = c & 127;
        f16x8 o;
#pragma unroll
        for (int j = 0; j < 8; ++j) o[j] = tile[kchunk * 8 + j][d];
        *(f16x8*)(outb + (size_t)c * 8) = o;
    }
}

// ---------- 256x256 GEMM, BK=64, 2-barrier overlapped, 32x32x16 MFMA ----------
// R10 schedule (known-good liveness: only Ahi reads outstanding at mid-barrier;
// S2-4 never touch Ahi). Inner math on mfma_f32_32x32x16_f16: 1.2x FLOP/cyc,
// 4x fewer MFMA instructions. C/D map (m74/m101, verified in our attn):
// D[row = (r&3)+8*(r>>2)+4*hi (+32*tile)][col = lane&31].
template <typename OutT>
__global__ __launch_bounds__(512, 1) void k_gemm256(const f16* __restrict__ A,
                                                    const f16* __restrict__ B,
                                                    OutT* __restrict__ C, int M, int N, int K) {
    extern __shared__ char smem[];
    f16* As = (f16*)smem;            // [2][256][64]
    f16* Bs = (f16*)smem + 32768;    // [2][256][64]
    const int tid = threadIdx.x, lane = tid & 63, w = tid >> 6;
    const int wr4 = w >> 1, wc2 = w & 1;
    const int l31 = lane & 31, hi = lane >> 5;
    const int nbx = gridDim.x;                 // n tiles: 16 (GEMM1) or 8 (GEMM2)
    const int bid0 = blockIdx.y * nbx + blockIdx.x;
    const int x = bid0 & 7, idx = bid0 >> 3;   // XCD id, local index
    const int snb = (nbx == 16) ? 3 : 2;       // log2(nbx/2)
    const int mt = (x >> 1) * 8 + (idx >> snb);
    const int nt_ = (x & 1) * (nbx >> 1) + (idx & ((nbx >> 1) - 1));
    const int m0 = mt * 256, n0 = nt_ * 256;
    const int KT = K >> 6;

    f32x16 acc[2][2][2] = {};   // [qr][qc][nt]
    f16x8 af[2][4], bf[2][2][4];

    auto stageA = [&](int buf, int half, int t) {
#pragma unroll
        for (int r = 0; r < 2; ++r) {
            int cb = r * 512 + w * 64;
            int c = cb + lane;
            int row = c >> 3, cc = c & 7;
            gld_lds16(A + (size_t)(m0 + half * 128 + row) * K + t * 64 + ((cc ^ (row & 7)) * 8),
                      As + buf * 16384 + half * 8192 + cb * 8);
        }
    };
    auto stageB = [&](int buf, int half, int t) {
#pragma unroll
        for (int r = 0; r < 2; ++r) {
            int cb = r * 512 + w * 64;
            int c = cb + lane;
            int row = c >> 3, cc = c & 7;
            gld_lds16(B + (size_t)(n0 + half * 128 + row) * K + t * 64 + ((cc ^ (row & 7)) * 8),
                      Bs + buf * 16384 + half * 8192 + cb * 8);
        }
    };
    // LDS slot s of row r holds global chunk s^(r&7); to read chunk g: slot g^(r&7).
    auto rdA32 = [&](int buf, int qr) {
        int R = qr * 128 + wr4 * 32 + l31;
#pragma unroll
        for (int ks = 0; ks < 4; ++ks)
            af[qr][ks] = *(const f16x8*)&As[buf * 16384 + R * 64 + (((2 * ks + hi) ^ (R & 7)) * 8)];
    };
    auto rdB32 = [&](int buf, int qc, int nt) {
        int R = qc * 128 + wc2 * 64 + nt * 32 + l31;
#pragma unroll
        for (int ks = 0; ks < 4; ++ks)
            bf[qc][nt][ks] = *(const f16x8*)&Bs[buf * 16384 + R * 64 + (((2 * ks + hi) ^ (R & 7)) * 8)];
    };

    // prologue: tile0 all 4 halves + tile1 {Alo,Blo,Bhi}; drain tile0's 8
    stageA(0, 0, 0); stageB(0, 0, 0); stageB(0, 1, 0); stageA(0, 1, 0);
    if (KT > 1) { stageA(1, 0, 1); stageB(1, 0, 1); stageB(1, 1, 1); }
    asm volatile("s_waitcnt vmcnt(6)");
    __builtin_amdgcn_s_barrier();

#pragma unroll 1
    for (int t = 0; t < KT; ++t) {
        const int buf = t & 1;
        // reads in order: Alo, Blo, Bhi, AHI LAST (only Ahi may be outstanding at mid-barrier)
        rdA32(buf, 0);
        rdB32(buf, 0, 0); rdB32(buf, 0, 1);
        rdB32(buf, 1, 0); rdB32(buf, 1, 1);
        rdA32(buf, 1);
        // M1: Q(0,0) = af[0] x bf[0][*]
        __builtin_amdgcn_s_setprio(1);
#pragma unroll
        for (int nt = 0; nt < 2; ++nt)
#pragma unroll
            for (int ks = 0; ks < 4; ++ks)
                acc[0][0][nt] = __builtin_amdgcn_mfma_f32_32x32x16_f16(af[0][ks], bf[0][nt][ks], acc[0][0][nt], 0, 0, 0);
        __builtin_amdgcn_s_setprio(0);
        if (t + 1 < KT) stageA(buf ^ 1, 1, t + 1);  // S1: Ahi(t+1) -> other buf
        // M2: Q(0,1) = af[0] x bf[1][*]
        __builtin_amdgcn_s_setprio(1);
#pragma unroll
        for (int nt = 0; nt < 2; ++nt)
#pragma unroll
            for (int ks = 0; ks < 4; ++ks)
                acc[0][1][nt] = __builtin_amdgcn_mfma_f32_32x32x16_f16(af[0][ks], bf[1][nt][ks], acc[0][1][nt], 0, 0, 0);
        __builtin_amdgcn_s_setprio(0);
        __builtin_amdgcn_s_barrier();   // Alo/Blo/Bhi of buf(t) fully consumed
        if (t + 2 < KT) { stageA(buf, 0, t + 2); stageB(buf, 0, t + 2); stageB(buf, 1, t + 2); }  // S2-4
        // M3: Q(1,1); M4: Q(1,0)
        __builtin_amdgcn_s_setprio(1);
#pragma unroll
        for (int nt = 0; nt < 2; ++nt)
#pragma unroll
            for (int ks = 0; ks < 4; ++ks)
                acc[1][1][nt] = __builtin_amdgcn_mfma_f32_32x32x16_f16(af[1][ks], bf[1][nt][ks], acc[1][1][nt], 0, 0, 0);
#pragma unroll
        for (int nt = 0; nt < 2; ++nt)
#pragma unroll
            for (int ks = 0; ks < 4; ++ks)
                acc[1][0][nt] = __builtin_amdgcn_mfma_f32_32x32x16_f16(af[1][ks], bf[0][nt][ks], acc[1][0][nt], 0, 0, 0);
        __builtin_amdgcn_s_setprio(0);
        if (t + 2 < KT)      asm volatile("s_waitcnt vmcnt(6)");
        else                 asm volatile("s_waitcnt vmcnt(0)");
        __builtin_amdgcn_s_barrier();
    }

    // epilogue: D[row=(r&3)+8*(r>>2)+4*hi][col=l31]
#pragma unroll
    for (int qr = 0; qr < 2; ++qr)
#pragma unroll
        for (int qc = 0; qc < 2; ++qc)
#pragma unroll
            for (int nt = 0; nt < 2; ++nt)
#pragma unroll
                for (int r = 0; r < 16; ++r) {
                    int row = m0 + qr * 128 + wr4 * 32 + (r & 3) + 8 * (r >> 2) + 4 * hi;
                    int col = n0 + qc * 128 + wc2 * 64 + nt * 32 + l31;
                    C[(size_t)row * N + col] = (OutT)acc[qr][qc][nt][r];
                }
}

// ---------- in-place xPos RoPE on qkv [8192][4096]; Q gets *scale*rsqrt(d), K gets /scale ----------
__global__ __launch_bounds__(256) void k_rope(f16* __restrict__ qkv, const float* __restrict__ tab) {
    int idx = blockIdx.x * 256 + threadIdx.x;
    const int QTOT = NBATCH * T_SEQ * 16 * 64;  // 8,388,608
    int f, col0, bt;
    bool isQ = idx < QTOT;
    if (isQ) {
        f = idx & 63; int hh = (idx >> 6) & 15; bt = idx >> 10;
        col0 = hh * 128 + f;
    } else {
        int j = idx - QTOT;
        f = j & 63; int hh = (j >> 6) & 7; bt = j >> 9;
        col0 = 2048 + hh * 128 + f;
    }
    int t = bt & (T_SEQ - 1);
    float cs = tab[t * 64 + f], sn = tab[131072 + t * 64 + f], sc = tab[262144 + t * 64 + f];
    float mult = isQ ? sc * 0.08838834764831845f : 1.0f / sc;  // fold 1/sqrt(128) into Q
    size_t p = (size_t)bt * 4096 + col0;
    float x1 = (float)qkv[p], x2 = (float)qkv[p + 64];
    qkv[p]      = (f16)((x1 * cs - x2 * sn) * mult);
    qkv[p + 64] = (f16)((x2 * cs + x1 * sn) * mult);
}

// ---------- causal GQA flash attention, v6: triple-buffered K/V ring, counted vmcnt ----------
__global__ __launch_bounds__(512) void k_attn(const f16* __restrict__ qkv,
                                              const f16* __restrict__ vtg,
                                              f16* __restrict__ ao) {
    extern __shared__ f16 asmem[];   // [3][16384]: per buf K 8192 | V 8192
    const int bid0 = blockIdx.x;
    const int bid = (bid0 & 7) * 32 + (bid0 >> 3);  // XCD swizzle (256 = 8x32)
    const int pr = bid & 7, kvh = (bid >> 3) & 7, b = bid >> 6;
    const int bk = b * 8 + kvh;
    const int tid = threadIdx.x, lane = tid & 63, w = tid >> 6;
    const int w4 = w & 3, hg = w >> 2;
    const int h = kvh * 2 + hg;
    const int l31 = lane & 31, hi = lane >> 5;

    const f16* kbase = qkv + (size_t)b * T_SEQ * 4096 + 2048 + kvh * 128;
    const f16* vbase = vtg + (size_t)bk * 32 * 8192;

    auto stage = [&](int buf, int kt) {
        f16* kb_ = asmem + buf * 16384;
        f16* vb_ = kb_ + 8192;
#pragma unroll
        for (int qq = 0; qq < 2; ++qq) {
            int c = w * 128 + qq * 64 + lane;
            int row = c >> 4;
            int ch = (c & 15) ^ (row & 15);
            gld_lds16(kbase + (size_t)(kt * 64 + row) * 4096 + ch * 8, kb_ + (w * 128 + qq * 64) * 8);
        }
#pragma unroll
        for (int qq = 0; qq < 2; ++qq) {
            int c = w * 128 + qq * 64 + lane;
            gld_lds16(vbase + ((size_t)kt * 1024 + c) * 8, vb_ + (w * 128 + qq * 64) * 8);
        }
    };

#pragma unroll 1
    for (int hf = 0; hf < 2; ++hf) {
        const int qt = hf ? pr : (15 - pr);
        const int q0 = qt * 128;
        const int nkt = 2 * qt + 2;  // even, >= 2
        const int qrow = q0 + w4 * 32 + l31;

        f16x8 qf[8];
#pragma unroll
        for (int ds = 0; ds < 8; ++ds)
            qf[ds] = *(const f16x8*)(qkv + (size_t)(b * T_SEQ + qrow) * 4096 + h * 128 + ds * 16 + hi * 8);

        f32x16 Ot[4] = {};
        float mrow = -1e30f, lrow = 0.0f;

        stage(0, 0);
        if (nkt > 1) stage(1, 1);

#pragma unroll 1
        for (int kt = 0; kt < nkt; ++kt) {
            const int kb = kt % 3;
            const f16* Kl = asmem + kb * 16384;
            const f16* Vl = Kl + 8192;
            // wait for THIS tile's loads only; kt+1's 4 loads stay in flight
            if (kt + 1 < nkt) asm volatile("s_waitcnt vmcnt(4)");
            else              asm volatile("s_waitcnt vmcnt(0)");
            __builtin_amdgcn_s_barrier();

            if (!(kt == 2 * qt + 1 && w4 < 2)) {
                // ---- St = K Q^T (swapped): lane q = l31, k rows in regs ----
                f32x16 St0 = {}, St1 = {};
                __builtin_amdgcn_s_setprio(1);
#pragma unroll
                for (int ds = 0; ds < 8; ++ds) {
                    int slot = (((2 * ds + hi) ^ (l31 & 15)) << 3);
                    f16x8 k0 = *(const f16x8*)&Kl[l31 * 128 + slot];
                    f16x8 k1 = *(const f16x8*)&Kl[(32 + l31) * 128 + slot];
                    St0 = __builtin_amdgcn_mfma_f32_32x32x16_f16(k0, qf[ds], St0, 0, 0, 0);
                    St1 = __builtin_amdgcn_mfma_f32_32x32x16_f16(k1, qf[ds], St1, 0, 0, 0);
                }
                __builtin_amdgcn_s_setprio(0);

                // ---- causal mask ----
                if (kt >= 2 * qt) {
                    int kbase2 = kt * 64;
#pragma unroll
                    for (int r = 0; r < 16; ++r) {
                        int krel = (r & 3) + 8 * (r >> 2) + 4 * hi;
                        if (kbase2 + krel > qrow) St0[r] = -1e30f;
                        if (kbase2 + 32 + krel > qrow) St1[r] = -1e30f;
                    }
                }

                // ---- in-register online softmax ----
                float tm[16];
#pragma unroll
                for (int r = 0; r < 16; ++r) tm[r] = fmaxf(St0[r], St1[r]);
#pragma unroll
                for (int d = 8; d >= 1; d >>= 1)
#pragma unroll
                    for (int r = 0; r < 8; ++r)
                        if (r < d) tm[r] = fmaxf(tm[r], tm[r + d]);
                float tmax = tm[0];
                float mtile = fmaxf(tmax, __shfl_xor(tmax, 32, 64));

                if (!__all((mtile - mrow) <= 8.0f)) {  // T13 defer-max
                    float mnew = fmaxf(mrow, mtile);
                    float fs = __expf(mrow - mnew);
                    mrow = mnew;
                    lrow *= fs;
#pragma unroll
                    for (int dblk = 0; dblk < 4; ++dblk)
#pragma unroll
                        for (int e = 0; e < 16; ++e) Ot[dblk][e] *= fs;
                }
#pragma unroll
                for (int r = 0; r < 16; ++r) {
                    St0[r] = __expf(St0[r] - mrow);
                    St1[r] = __expf(St1[r] - mrow);
                }
                float ts[16];
#pragma unroll
                for (int r = 0; r < 16; ++r) ts[r] = St0[r] + St1[r];
#pragma unroll
                for (int d = 8; d >= 1; d >>= 1)
#pragma unroll
                    for (int r = 0; r < 8; ++r)
                        if (r < d) ts[r] += ts[r + d];
                float tsum = ts[0];
                lrow += tsum + __shfl_xor(tsum, 32, 64);

                // ---- pack P (cvt_pkrtz + shfl_xor 32) + PV ----
#define PV_P(o, pos) ((o) < 4 ? St0[((o) & 3) * 4 + (pos)] : St1[((o) & 3) * 4 + (pos)])
#pragma unroll
                for (int s = 0; s < 4; ++s) {
                    unsigned x1 = pk2(PV_P(2 * s, 0), PV_P(2 * s, 1));
                    unsigned x2 = pk2(PV_P(2 * s, 2), PV_P(2 * s, 3));
                    unsigned y1 = pk2(PV_P(2 * s + 1, 0), PV_P(2 * s + 1, 1));
                    unsigned y2 = pk2(PV_P(2 * s + 1, 2), PV_P(2 * s + 1, 3));
                    unsigned sx1 = __shfl_xor(x1, 32, 64);
                    unsigned sx2 = __shfl_xor(x2, 32, 64);
                    unsigned sy1 = __shfl_xor(y1, 32, 64);
                    unsigned sy2 = __shfl_xor(y2, 32, 64);
                    u32x4 pw;
                    pw[0] = hi ? sy1 : x1;
                    pw[1] = hi ? sy2 : x2;
                    pw[2] = hi ? y1 : sx1;
                    pw[3] = hi ? y2 : sx2;
                    f16x8 pa = __builtin_bit_cast(f16x8, pw);
                    __builtin_amdgcn_s_setprio(1);
#pragma unroll
                    for (int dblk = 0; dblk < 4; ++dblk) {
                        f16x8 vb = *(const f16x8*)&Vl[(((2 * s + hi) << 7) + 32 * dblk + l31) << 3];
                        Ot[dblk] = __builtin_amdgcn_mfma_f32_32x32x16_f16(vb, pa, Ot[dblk], 0, 0, 0);
                    }
                    __builtin_amdgcn_s_setprio(0);
                }
#undef PV_P
            }
            __builtin_amdgcn_s_barrier();  // all reads of buf kb done before its next writer issues
            if (kt + 2 < nkt) stage((kt + 2) % 3, kt + 2);
        }

        // ---- epilogue ----
        {
            float inv = 1.0f / lrow;
            size_t rowb = (size_t)(b * T_SEQ + qrow) * 2048 + h * 128;
#pragma unroll
            for (int dblk = 0; dblk < 4; ++dblk)
#pragma unroll
                for (int rg = 0; rg < 4; ++rg) {
                    f16x4 o4 = { (f16)(Ot[dblk][rg * 4 + 0] * inv), (f16)(Ot[dblk][rg * 4 + 1] * inv),
                                 (f16)(Ot[dblk][rg * 4 + 2] * inv), (f16)(Ot[dblk][rg * 4 + 3] * inv) };
                    *(f16x4*)(ao + rowb + dblk * 32 + rg * 8 + hi * 4) = o4;
                }
        }
    }
}

extern "C" void kernel_launch(void* const* d_in, const int* in_sizes, int n_in,
                              void* d_out, int out_size, void* d_ws, size_t ws_size,
                              hipStream_t stream) {
    const float* x  = (const float*)d_in[0];
    const float* Wq = (const float*)d_in[1];
    const float* Wk = (const float*)d_in[2];
    const float* Wv = (const float*)d_in[3];
    const float* Wo = (const float*)d_in[4];
    float* out = (float*)d_out;

    // workspace (fp16 elems): xh 16.7M | wqkvT 8.4M | woT 4.2M | qkv 33.5M | tab (f32)
    f16* xh    = (f16*)d_ws;
    f16* wqkvT = xh + (size_t)16777216;
    f16* woT   = wqkvT + (size_t)8388608;
    f16* qkv   = woT + (size_t)4194304;
    float* tab = (float*)(qkv + (size_t)33554432);
    f16* ao  = xh;     // alias: xh dead after GEMM1
    f16* vtg = wqkvT;  // alias: wqkvT dead after GEMM1 (8.4M f16 = exact fit)

    hipFuncSetAttribute(reinterpret_cast<const void*>(&k_gemm256<f16>),
                        hipFuncAttributeMaxDynamicSharedMemorySize, 131072);
    hipFuncSetAttribute(reinterpret_cast<const void*>(&k_gemm256<float>),
                        hipFuncAttributeMaxDynamicSharedMemorySize, 131072);
    hipFuncSetAttribute(reinterpret_cast<const void*>(&k_attn),
                        hipFuncAttributeMaxDynamicSharedMemorySize, 98304);

    k_prep<<<29184, 256, 0, stream>>>(x, Wq, Wk, Wv, Wo, xh, wqkvT, woT, tab);
    // QKV projection: qkv[8192][4096]
    k_gemm256<f16><<<dim3(16, 32), 512, 131072, stream>>>(xh, wqkvT, qkv, 8192, 4096, 2048);
    k_vtrans<<<dim3(32, 32), 256, 0, stream>>>(qkv, vtg);
    k_rope<<<49152, 256, 0, stream>>>(qkv, tab);
    k_attn<<<256, 512, 98304, stream>>>(qkv, vtg, ao);
    // output projection -> fp32
    k_gemm256<float><<<dim3(8, 32), 512, 131072, stream>>>(ao, woT, out, 8192, 2048, 2048);
}

// Round 15
// 366.320 us; speedup vs baseline: 5.8523x; 1.0834x over previous
//
#include <hip/hip_runtime.h>

typedef _Float16 f16;
typedef __attribute__((ext_vector_type(8))) _Float16 f16x8;
typedef __attribute__((ext_vector_type(4))) _Float16 f16x4;
typedef __attribute__((ext_vector_type(4))) float f32x4;
typedef __attribute__((ext_vector_type(16))) float f32x16;
typedef __attribute__((ext_vector_type(4))) unsigned u32x4;

#define T_SEQ 2048
#define NBATCH 4

__device__ __forceinline__ void gld_lds16(const f16* g, f16* l) {
    __builtin_amdgcn_global_load_lds((const __attribute__((address_space(1))) void*)g,
                                     (__attribute__((address_space(3))) void*)l, 16, 0, 0);
}

__device__ __forceinline__ unsigned pk2(float a, float b) {
    __attribute__((ext_vector_type(2))) __fp16 h = __builtin_amdgcn_cvt_pkrtz(a, b);
    return __builtin_bit_cast(unsigned, h);
}

// ---------- fused prep: cast x | transpose Wq/Wk/Wv/Wo | xPos tables ----------
__global__ __launch_bounds__(256) void k_prep(const float* __restrict__ x,
                                              const float* __restrict__ Wq,
                                              const float* __restrict__ Wk,
                                              const float* __restrict__ Wv,
                                              const float* __restrict__ Wo,
                                              f16* __restrict__ xh,
                                              f16* __restrict__ wqkvT,
                                              f16* __restrict__ woT,
                                              float* __restrict__ tab) {
    __shared__ float tile[32][33];
    int bidx = blockIdx.x;
    if (bidx < 16384) {  // cast x fp32 -> fp16 (float4 per thread)
        int i = bidx * 256 + threadIdx.x;
        float4 v = ((const float4*)x)[i];
        f16x4 o = { (f16)v.x, (f16)v.y, (f16)v.z, (f16)v.w };
        ((f16x4*)xh)[i] = o;
        return;
    }
    bidx -= 16384;
    if (bidx >= 12288) {  // tables: cos | sin | scale, each [T][64] fp32
        int i = (bidx - 12288) * 256 + threadIdx.x;  // 131072 total
        int t = i >> 6, f = i & 63;
        float inv_freq = powf(10000.0f, -(2.0f * f) / 128.0f);
        float ang = (float)t * inv_freq;
        float sv = (2.0f * f + 51.2f) / 179.2f;
        float pw = ((float)t - 1024.0f) / 512.0f;
        tab[i] = cosf(ang);
        tab[131072 + i] = sinf(ang);
        tab[262144 + i] = powf(sv, pw);
        return;
    }
    // weight transpose+cast: dst[n][k] = (f16)src[k][n], K=2048
    const float* src; f16* dst; int N, bx, by;
    if (bidx < 4096)      { src = Wq; dst = wqkvT;                      N = 2048; bx = bidx & 63; by = bidx >> 6; }
    else if (bidx < 6144) { src = Wk; dst = wqkvT + (size_t)2048 * 2048; N = 1024; int t2 = bidx - 4096; bx = t2 & 31; by = t2 >> 5; }
    else if (bidx < 8192) { src = Wv; dst = wqkvT + (size_t)3072 * 2048; N = 1024; int t2 = bidx - 6144; bx = t2 & 31; by = t2 >> 5; }
    else                  { src = Wo; dst = woT;                        N = 2048; int t2 = bidx - 8192; bx = t2 & 63; by = t2 >> 6; }
    int n0 = bx * 32, k0 = by * 32;
    int tx = threadIdx.x & 31, ty = threadIdx.x >> 5;  // 32 x 8
#pragma unroll
    for (int j = 0; j < 32; j += 8)
        tile[ty + j][tx] = src[(size_t)(k0 + ty + j) * N + n0 + tx];
    __syncthreads();
#pragma unroll
    for (int j = 0; j < 32; j += 8)
        dst[(size_t)(n0 + ty + j) * 2048 + k0 + tx] = (f16)tile[tx][ty + j];
}

// ---------- fused post-GEMM1: V blocked-transpose | in-place xPos RoPE ----------
// blocks [0,1024): vtrans (V region, read-only). blocks [1024,50176): rope (Q/K
// regions, in-place). Disjoint qkv regions -> no ordering hazard in one launch.
__global__ __launch_bounds__(256) void k_post(f16* __restrict__ qkv,
                                              f16* __restrict__ vtg,
                                              const float* __restrict__ tab) {
    int bidx = blockIdx.x;
    const int tid = threadIdx.x;
    if (bidx < 1024) {  // ---- vtrans ----
        const int kt = bidx & 31, bk = bidx >> 5;
        const int b = bk >> 3, kvh = bk & 7;
        __shared__ f16 tile[64][132];
#pragma unroll
        for (int p = 0; p < 4; ++p) {
            int idx = p * 256 + tid;
            int r = idx >> 4, dc = (idx & 15) * 8;
            f16x8 v = *(const f16x8*)(qkv + (size_t)(b * T_SEQ + kt * 64 + r) * 4096 + 3072 + kvh * 128 + dc);
#pragma unroll
            for (int j = 0; j < 8; ++j) tile[r][dc + j] = v[j];
        }
        __syncthreads();
        f16* outb = vtg + (size_t)(bk * 32 + kt) * 8192;
#pragma unroll
        for (int p = 0; p < 4; ++p) {
            int c = p * 256 + tid;
            int kchunk = c >> 7, d = c & 127;
            f16x8 o;
#pragma unroll
            for (int j = 0; j < 8; ++j) o[j] = tile[kchunk * 8 + j][d];
            *(f16x8*)(outb + (size_t)c * 8) = o;
        }
        return;
    }
    // ---- rope ----
    int idx = (bidx - 1024) * 256 + tid;
    const int QTOT = NBATCH * T_SEQ * 16 * 64;  // 8,388,608
    int f, col0, bt;
    bool isQ = idx < QTOT;
    if (isQ) {
        f = idx & 63; int hh = (idx >> 6) & 15; bt = idx >> 10;
        col0 = hh * 128 + f;
    } else {
        int j = idx - QTOT;
        f = j & 63; int hh = (j >> 6) & 7; bt = j >> 9;
        col0 = 2048 + hh * 128 + f;
    }
    int t = bt & (T_SEQ - 1);
    float cs = tab[t * 64 + f], sn = tab[131072 + t * 64 + f], sc = tab[262144 + t * 64 + f];
    float mult = isQ ? sc * 0.08838834764831845f : 1.0f / sc;  // fold 1/sqrt(128) into Q
    size_t p = (size_t)bt * 4096 + col0;
    float x1 = (float)qkv[p], x2 = (float)qkv[p + 64];
    qkv[p]      = (f16)((x1 * cs - x2 * sn) * mult);
    qkv[p + 64] = (f16)((x2 * cs + x1 * sn) * mult);
}

// ---------- 256x256 GEMM, 2-barrier overlapped K-loop (R10 known-good) ----------
// All 24 frag ds_reads issue at tile start; M1/M2 consume aL/bL/bH before the mid
// barrier, proving Alo/Blo/Bhi slots dead before S2-4 overwrite them. aH's slot is
// only written by S1 of the NEXT tile (after the end barrier).
template <typename OutT>
__global__ __launch_bounds__(512, 1) void k_gemm256(const f16* __restrict__ A,
                                                    const f16* __restrict__ B,
                                                    OutT* __restrict__ C, int M, int N, int K) {
    extern __shared__ char smem[];
    f16* As = (f16*)smem;            // [2][256][64]
    f16* Bs = (f16*)smem + 32768;    // [2][256][64]
    const int tid = threadIdx.x, lane = tid & 63, w = tid >> 6;
    const int wr4 = w >> 1, wc2 = w & 1;
    const int cq = lane & 15, gq = lane >> 4;
    const int nbx = gridDim.x;                 // n tiles: 16 (GEMM1) or 8 (GEMM2)
    const int bid0 = blockIdx.y * nbx + blockIdx.x;
    const int x = bid0 & 7, idx = bid0 >> 3;   // XCD id, local index
    const int snb = (nbx == 16) ? 3 : 2;       // log2(nbx/2)
    const int mt = (x >> 1) * 8 + (idx >> snb);
    const int nt = (x & 1) * (nbx >> 1) + (idx & ((nbx >> 1) - 1));
    const int m0 = mt * 256, n0 = nt * 256;
    const int KT = K >> 6;

    f32x4 acc[2][2][2][4] = {};
    f16x8 aL[2][2], aH[2][2], bL[4][2], bH[4][2];

    auto stageA = [&](int buf, int half, int t) {
#pragma unroll
        for (int r = 0; r < 2; ++r) {
            int cb = r * 512 + w * 64;
            int c = cb + lane;
            int row = c >> 3, cc = c & 7;
            gld_lds16(A + (size_t)(m0 + half * 128 + row) * K + t * 64 + ((cc ^ (row & 7)) * 8),
                      As + buf * 16384 + half * 8192 + cb * 8);
        }
    };
    auto stageB = [&](int buf, int half, int t) {
#pragma unroll
        for (int r = 0; r < 2; ++r) {
            int cb = r * 512 + w * 64;
            int c = cb + lane;
            int row = c >> 3, cc = c & 7;
            gld_lds16(B + (size_t)(n0 + half * 128 + row) * K + t * 64 + ((cc ^ (row & 7)) * 8),
                      Bs + buf * 16384 + half * 8192 + cb * 8);
        }
    };
    auto rdA = [&](int buf, int qr, f16x8 a[2][2]) {
#pragma unroll
        for (int mi = 0; mi < 2; ++mi)
#pragma unroll
            for (int ks = 0; ks < 2; ++ks) {
                int R = qr * 128 + wr4 * 32 + mi * 16 + cq;
                a[mi][ks] = *(const f16x8*)&As[buf * 16384 + R * 64 + (((ks * 4 + gq) ^ (cq & 7)) * 8)];
            }
    };
    auto rdB = [&](int buf, int qc, f16x8 b[4][2]) {
#pragma unroll
        for (int ni = 0; ni < 4; ++ni)
#pragma unroll
            for (int ks = 0; ks < 2; ++ks) {
                int R = qc * 128 + wc2 * 64 + ni * 16 + cq;
                b[ni][ks] = *(const f16x8*)&Bs[buf * 16384 + R * 64 + (((ks * 4 + gq) ^ (cq & 7)) * 8)];
            }
    };

    // prologue: tile0 all 4 halves + tile1 {Alo,Blo,Bhi}; drain tile0's 8
    stageA(0, 0, 0); stageB(0, 0, 0); stageB(0, 1, 0); stageA(0, 1, 0);
    if (KT > 1) { stageA(1, 0, 1); stageB(1, 0, 1); stageB(1, 1, 1); }
    asm volatile("s_waitcnt vmcnt(6)");
    __builtin_amdgcn_s_barrier();

#pragma unroll 1
    for (int t = 0; t < KT; ++t) {
        const int buf = t & 1;
        // issue ALL fragment reads for this tile (reads overlap MFMA below)
        rdA(buf, 0, aL); rdB(buf, 0, bL); rdB(buf, 1, bH); rdA(buf, 1, aH);
        // M1: Q(0,0) = aL x bL
        __builtin_amdgcn_s_setprio(1);
#pragma unroll
        for (int mi = 0; mi < 2; ++mi)
#pragma unroll
            for (int ni = 0; ni < 4; ++ni)
#pragma unroll
                for (int ks = 0; ks < 2; ++ks)
                    acc[0][0][mi][ni] = __builtin_amdgcn_mfma_f32_16x16x32_f16(aL[mi][ks], bL[ni][ks], acc[0][0][mi][ni], 0, 0, 0);
        __builtin_amdgcn_s_setprio(0);
        if (t + 1 < KT) stageA(buf ^ 1, 1, t + 1);  // S1: Ahi(t+1) -> other buf
        // M2: Q(0,1) = aL x bH
        __builtin_amdgcn_s_setprio(1);
#pragma unroll
        for (int mi = 0; mi < 2; ++mi)
#pragma unroll
            for (int ni = 0; ni < 4; ++ni)
#pragma unroll
                for (int ks = 0; ks < 2; ++ks)
                    acc[0][1][mi][ni] = __builtin_amdgcn_mfma_f32_16x16x32_f16(aL[mi][ks], bH[ni][ks], acc[0][1][mi][ni], 0, 0, 0);
        __builtin_amdgcn_s_setprio(0);
        // all waves consumed aL/bL/bH (M1,M2 done) -> Alo/Blo/Bhi slots dead
        __builtin_amdgcn_s_barrier();
        if (t + 2 < KT) { stageA(buf, 0, t + 2); stageB(buf, 0, t + 2); stageB(buf, 1, t + 2); }  // S2-4
        // M3: Q(1,1) = aH x bH ; M4: Q(1,0) = aH x bL
        __builtin_amdgcn_s_setprio(1);
#pragma unroll
        for (int mi = 0; mi < 2; ++mi)
#pragma unroll
            for (int ni = 0; ni < 4; ++ni)
#pragma unroll
                for (int ks = 0; ks < 2; ++ks)
                    acc[1][1][mi][ni] = __builtin_amdgcn_mfma_f32_16x16x32_f16(aH[mi][ks], bH[ni][ks], acc[1][1][mi][ni], 0, 0, 0);
#pragma unroll
        for (int mi = 0; mi < 2; ++mi)
#pragma unroll
            for (int ni = 0; ni < 4; ++ni)
#pragma unroll
                for (int ks = 0; ks < 2; ++ks)
                    acc[1][0][mi][ni] = __builtin_amdgcn_mfma_f32_16x16x32_f16(aH[mi][ks], bL[ni][ks], acc[1][0][mi][ni], 0, 0, 0);
        __builtin_amdgcn_s_setprio(0);
        // counted drain: all of tile t+1 arrives; t+2's 3 half-tiles stay in flight
        if (t + 2 < KT)      asm volatile("s_waitcnt vmcnt(6)");
        else                 asm volatile("s_waitcnt vmcnt(0)");
        __builtin_amdgcn_s_barrier();
    }

#pragma unroll
    for (int qr = 0; qr < 2; ++qr)
#pragma unroll
        for (int qc = 0; qc < 2; ++qc)
#pragma unroll
            for (int mi = 0; mi < 2; ++mi)
#pragma unroll
                for (int ni = 0; ni < 4; ++ni)
#pragma unroll
                    for (int i = 0; i < 4; ++i) {
                        int row = m0 + qr * 128 + wr4 * 32 + mi * 16 + gq * 4 + i;
                        int col = n0 + qc * 128 + wc2 * 64 + ni * 16 + cq;
                        C[(size_t)row * N + col] = (OutT)acc[qr][qc][mi][ni][i];
                    }
}

// ---------- causal GQA flash attention, v6: triple-buffered K/V ring, counted vmcnt ----------
__global__ __launch_bounds__(512) void k_attn(const f16* __restrict__ qkv,
                                              const f16* __restrict__ vtg,
                                              f16* __restrict__ ao) {
    extern __shared__ f16 asmem[];   // [3][16384]: per buf K 8192 | V 8192
    const int bid0 = blockIdx.x;
    const int bid = (bid0 & 7) * 32 + (bid0 >> 3);  // XCD swizzle (256 = 8x32)
    const int pr = bid & 7, kvh = (bid >> 3) & 7, b = bid >> 6;
    const int bk = b * 8 + kvh;
    const int tid = threadIdx.x, lane = tid & 63, w = tid >> 6;
    const int w4 = w & 3, hg = w >> 2;
    const int h = kvh * 2 + hg;
    const int l31 = lane & 31, hi = lane >> 5;

    const f16* kbase = qkv + (size_t)b * T_SEQ * 4096 + 2048 + kvh * 128;
    const f16* vbase = vtg + (size_t)bk * 32 * 8192;

    auto stage = [&](int buf, int kt) {
        f16* kb_ = asmem + buf * 16384;
        f16* vb_ = kb_ + 8192;
#pragma unroll
        for (int qq = 0; qq < 2; ++qq) {
            int c = w * 128 + qq * 64 + lane;
            int row = c >> 4;
            int ch = (c & 15) ^ (row & 15);
            gld_lds16(kbase + (size_t)(kt * 64 + row) * 4096 + ch * 8, kb_ + (w * 128 + qq * 64) * 8);
        }
#pragma unroll
        for (int qq = 0; qq < 2; ++qq) {
            int c = w * 128 + qq * 64 + lane;
            gld_lds16(vbase + ((size_t)kt * 1024 + c) * 8, vb_ + (w * 128 + qq * 64) * 8);
        }
    };

#pragma unroll 1
    for (int hf = 0; hf < 2; ++hf) {
        const int qt = hf ? pr : (15 - pr);
        const int q0 = qt * 128;
        const int nkt = 2 * qt + 2;  // even, >= 2
        const int qrow = q0 + w4 * 32 + l31;

        f16x8 qf[8];
#pragma unroll
        for (int ds = 0; ds < 8; ++ds)
            qf[ds] = *(const f16x8*)(qkv + (size_t)(b * T_SEQ + qrow) * 4096 + h * 128 + ds * 16 + hi * 8);

        f32x16 Ot[4] = {};
        float mrow = -1e30f, lrow = 0.0f;

        stage(0, 0);
        if (nkt > 1) stage(1, 1);

#pragma unroll 1
        for (int kt = 0; kt < nkt; ++kt) {
            const int kb = kt % 3;
            const f16* Kl = asmem + kb * 16384;
            const f16* Vl = Kl + 8192;
            // wait for THIS tile's loads only; kt+1's 4 loads stay in flight
            if (kt + 1 < nkt) asm volatile("s_waitcnt vmcnt(4)");
            else              asm volatile("s_waitcnt vmcnt(0)");
            __builtin_amdgcn_s_barrier();

            if (!(kt == 2 * qt + 1 && w4 < 2)) {
                // ---- St = K Q^T (swapped): lane q = l31, k rows in regs ----
                f32x16 St0 = {}, St1 = {};
                __builtin_amdgcn_s_setprio(1);
#pragma unroll
                for (int ds = 0; ds < 8; ++ds) {
                    int slot = (((2 * ds + hi) ^ (l31 & 15)) << 3);
                    f16x8 k0 = *(const f16x8*)&Kl[l31 * 128 + slot];
                    f16x8 k1 = *(const f16x8*)&Kl[(32 + l31) * 128 + slot];
                    St0 = __builtin_amdgcn_mfma_f32_32x32x16_f16(k0, qf[ds], St0, 0, 0, 0);
                    St1 = __builtin_amdgcn_mfma_f32_32x32x16_f16(k1, qf[ds], St1, 0, 0, 0);
                }
                __builtin_amdgcn_s_setprio(0);

                // ---- causal mask ----
                if (kt >= 2 * qt) {
                    int kbase2 = kt * 64;
#pragma unroll
                    for (int r = 0; r < 16; ++r) {
                        int krel = (r & 3) + 8 * (r >> 2) + 4 * hi;
                        if (kbase2 + krel > qrow) St0[r] = -1e30f;
                        if (kbase2 + 32 + krel > qrow) St1[r] = -1e30f;
                    }
                }

                // ---- in-register online softmax ----
                float tm[16];
#pragma unroll
                for (int r = 0; r < 16; ++r) tm[r] = fmaxf(St0[r], St1[r]);
#pragma unroll
                for (int d = 8; d >= 1; d >>= 1)
#pragma unroll
                    for (int r = 0; r < 8; ++r)
                        if (r < d) tm[r] = fmaxf(tm[r], tm[r + d]);
                float tmax = tm[0];
                float mtile = fmaxf(tmax, __shfl_xor(tmax, 32, 64));

                if (!__all((mtile - mrow) <= 8.0f)) {  // T13 defer-max
                    float mnew = fmaxf(mrow, mtile);
                    float fs = __expf(mrow - mnew);
                    mrow = mnew;
                    lrow *= fs;
#pragma unroll
                    for (int dblk = 0; dblk < 4; ++dblk)
#pragma unroll
                        for (int e = 0; e < 16; ++e) Ot[dblk][e] *= fs;
                }
#pragma unroll
                for (int r = 0; r < 16; ++r) {
                    St0[r] = __expf(St0[r] - mrow);
                    St1[r] = __expf(St1[r] - mrow);
                }
                float ts[16];
#pragma unroll
                for (int r = 0; r < 16; ++r) ts[r] = St0[r] + St1[r];
#pragma unroll
                for (int d = 8; d >= 1; d >>= 1)
#pragma unroll
                    for (int r = 0; r < 8; ++r)
                        if (r < d) ts[r] += ts[r + d];
                float tsum = ts[0];
                lrow += tsum + __shfl_xor(tsum, 32, 64);

                // ---- pack P (cvt_pkrtz + shfl_xor 32) + PV ----
#define PV_P(o, pos) ((o) < 4 ? St0[((o) & 3) * 4 + (pos)] : St1[((o) & 3) * 4 + (pos)])
#pragma unroll
                for (int s = 0; s < 4; ++s) {
                    unsigned x1 = pk2(PV_P(2 * s, 0), PV_P(2 * s, 1));
                    unsigned x2 = pk2(PV_P(2 * s, 2), PV_P(2 * s, 3));
                    unsigned y1 = pk2(PV_P(2 * s + 1, 0), PV_P(2 * s + 1, 1));
                    unsigned y2 = pk2(PV_P(2 * s + 1, 2), PV_P(2 * s + 1, 3));
                    unsigned sx1 = __shfl_xor(x1, 32, 64);
                    unsigned sx2 = __shfl_xor(x2, 32, 64);
                    unsigned sy1 = __shfl_xor(y1, 32, 64);
                    unsigned sy2 = __shfl_xor(y2, 32, 64);
                    u32x4 pw;
                    pw[0] = hi ? sy1 : x1;
                    pw[1] = hi ? sy2 : x2;
                    pw[2] = hi ? y1 : sx1;
                    pw[3] = hi ? y2 : sx2;
                    f16x8 pa = __builtin_bit_cast(f16x8, pw);
                    __builtin_amdgcn_s_setprio(1);
#pragma unroll
                    for (int dblk = 0; dblk < 4; ++dblk) {
                        f16x8 vb = *(const f16x8*)&Vl[(((2 * s + hi) << 7) + 32 * dblk + l31) << 3];
                        Ot[dblk] = __builtin_amdgcn_mfma_f32_32x32x16_f16(vb, pa, Ot[dblk], 0, 0, 0);
                    }
                    __builtin_amdgcn_s_setprio(0);
                }
#undef PV_P
            }
            __builtin_amdgcn_s_barrier();  // all reads of buf kb done before its next writer issues
            if (kt + 2 < nkt) stage((kt + 2) % 3, kt + 2);
        }

        // ---- epilogue ----
        {
            float inv = 1.0f / lrow;
            size_t rowb = (size_t)(b * T_SEQ + qrow) * 2048 + h * 128;
#pragma unroll
            for (int dblk = 0; dblk < 4; ++dblk)
#pragma unroll
                for (int rg = 0; rg < 4; ++rg) {
                    f16x4 o4 = { (f16)(Ot[dblk][rg * 4 + 0] * inv), (f16)(Ot[dblk][rg * 4 + 1] * inv),
                                 (f16)(Ot[dblk][rg * 4 + 2] * inv), (f16)(Ot[dblk][rg * 4 + 3] * inv) };
                    *(f16x4*)(ao + rowb + dblk * 32 + rg * 8 + hi * 4) = o4;
                }
        }
    }
}

extern "C" void kernel_launch(void* const* d_in, const int* in_sizes, int n_in,
                              void* d_out, int out_size, void* d_ws, size_t ws_size,
                              hipStream_t stream) {
    const float* x  = (const float*)d_in[0];
    const float* Wq = (const float*)d_in[1];
    const float* Wk = (const float*)d_in[2];
    const float* Wv = (const float*)d_in[3];
    const float* Wo = (const float*)d_in[4];
    float* out = (float*)d_out;

    // workspace (fp16 elems): xh 16.7M | wqkvT 8.4M | woT 4.2M | qkv 33.5M | tab (f32)
    f16* xh    = (f16*)d_ws;
    f16* wqkvT = xh + (size_t)16777216;
    f16* woT   = wqkvT + (size_t)8388608;
    f16* qkv   = woT + (size_t)4194304;
    float* tab = (float*)(qkv + (size_t)33554432);
    f16* ao  = xh;     // alias: xh dead after GEMM1
    f16* vtg = wqkvT;  // alias: wqkvT dead after GEMM1 (8.4M f16 = exact fit)

    hipFuncSetAttribute(reinterpret_cast<const void*>(&k_gemm256<f16>),
                        hipFuncAttributeMaxDynamicSharedMemorySize, 131072);
    hipFuncSetAttribute(reinterpret_cast<const void*>(&k_gemm256<float>),
                        hipFuncAttributeMaxDynamicSharedMemorySize, 131072);
    hipFuncSetAttribute(reinterpret_cast<const void*>(&k_attn),
                        hipFuncAttributeMaxDynamicSharedMemorySize, 98304);

    k_prep<<<29184, 256, 0, stream>>>(x, Wq, Wk, Wv, Wo, xh, wqkvT, woT, tab);
    // QKV projection: qkv[8192][4096]
    k_gemm256<f16><<<dim3(16, 32), 512, 131072, stream>>>(xh, wqkvT, qkv, 8192, 4096, 2048);
    // fused vtrans + rope (disjoint qkv regions)
    k_post<<<50176, 256, 0, stream>>>(qkv, vtg, tab);
    k_attn<<<256, 512, 98304, stream>>>(qkv, vtg, ao);
    // output projection -> fp32
    k_gemm256<float><<<dim3(8, 32), 512, 131072, stream>>>(ao, woT, out, 8192, 2048, 2048);
}

// Round 16
// 366.159 us; speedup vs baseline: 5.8549x; 1.0004x over previous
//
#include <hip/hip_runtime.h>

typedef _Float16 f16;
typedef __attribute__((ext_vector_type(8))) _Float16 f16x8;
typedef __attribute__((ext_vector_type(4))) _Float16 f16x4;
typedef __attribute__((ext_vector_type(4))) float f32x4;
typedef __attribute__((ext_vector_type(16))) float f32x16;
typedef __attribute__((ext_vector_type(4))) unsigned u32x4;

#define T_SEQ 2048
#define NBATCH 4

__device__ __forceinline__ void gld_lds16(const f16* g, f16* l) {
    __builtin_amdgcn_global_load_lds((const __attribute__((address_space(1))) void*)g,
                                     (__attribute__((address_space(3))) void*)l, 16, 0, 0);
}

__device__ __forceinline__ unsigned pk2(float a, float b) {
    __attribute__((ext_vector_type(2))) __fp16 h = __builtin_amdgcn_cvt_pkrtz(a, b);
    return __builtin_bit_cast(unsigned, h);
}

// ---------- fused prep: cast x | transpose Wq/Wk/Wv/Wo | xPos tables ----------
__global__ __launch_bounds__(256) void k_prep(const float* __restrict__ x,
                                              const float* __restrict__ Wq,
                                              const float* __restrict__ Wk,
                                              const float* __restrict__ Wv,
                                              const float* __restrict__ Wo,
                                              f16* __restrict__ xh,
                                              f16* __restrict__ wqkvT,
                                              f16* __restrict__ woT,
                                              float* __restrict__ tab) {
    __shared__ float tile[32][33];
    int bidx = blockIdx.x;
    if (bidx < 16384) {  // cast x fp32 -> fp16 (float4 per thread)
        int i = bidx * 256 + threadIdx.x;
        float4 v = ((const float4*)x)[i];
        f16x4 o = { (f16)v.x, (f16)v.y, (f16)v.z, (f16)v.w };
        ((f16x4*)xh)[i] = o;
        return;
    }
    bidx -= 16384;
    if (bidx >= 12288) {  // tables: cos | sin | scale, each [T][64] fp32
        int i = (bidx - 12288) * 256 + threadIdx.x;  // 131072 total
        int t = i >> 6, f = i & 63;
        float inv_freq = powf(10000.0f, -(2.0f * f) / 128.0f);
        float ang = (float)t * inv_freq;
        float sv = (2.0f * f + 51.2f) / 179.2f;
        float pw = ((float)t - 1024.0f) / 512.0f;
        tab[i] = cosf(ang);
        tab[131072 + i] = sinf(ang);
        tab[262144 + i] = powf(sv, pw);
        return;
    }
    // weight transpose+cast: dst[n][k] = (f16)src[k][n], K=2048
    const float* src; f16* dst; int N, bx, by;
    if (bidx < 4096)      { src = Wq; dst = wqkvT;                      N = 2048; bx = bidx & 63; by = bidx >> 6; }
    else if (bidx < 6144) { src = Wk; dst = wqkvT + (size_t)2048 * 2048; N = 1024; int t2 = bidx - 4096; bx = t2 & 31; by = t2 >> 5; }
    else if (bidx < 8192) { src = Wv; dst = wqkvT + (size_t)3072 * 2048; N = 1024; int t2 = bidx - 6144; bx = t2 & 31; by = t2 >> 5; }
    else                  { src = Wo; dst = woT;                        N = 2048; int t2 = bidx - 8192; bx = t2 & 63; by = t2 >> 6; }
    int n0 = bx * 32, k0 = by * 32;
    int tx = threadIdx.x & 31, ty = threadIdx.x >> 5;  // 32 x 8
#pragma unroll
    for (int j = 0; j < 32; j += 8)
        tile[ty + j][tx] = src[(size_t)(k0 + ty + j) * N + n0 + tx];
    __syncthreads();
#pragma unroll
    for (int j = 0; j < 32; j += 8)
        dst[(size_t)(n0 + ty + j) * 2048 + k0 + tx] = (f16)tile[tx][ty + j];
}

// ---------- fused post-GEMM1: V blocked-transpose | in-place xPos RoPE ----------
__global__ __launch_bounds__(256) void k_post(f16* __restrict__ qkv,
                                              f16* __restrict__ vtg,
                                              const float* __restrict__ tab) {
    int bidx = blockIdx.x;
    const int tid = threadIdx.x;
    if (bidx < 1024) {  // ---- vtrans ----
        const int kt = bidx & 31, bk = bidx >> 5;
        const int b = bk >> 3, kvh = bk & 7;
        __shared__ f16 tile[64][132];
#pragma unroll
        for (int p = 0; p < 4; ++p) {
            int idx = p * 256 + tid;
            int r = idx >> 4, dc = (idx & 15) * 8;
            f16x8 v = *(const f16x8*)(qkv + (size_t)(b * T_SEQ + kt * 64 + r) * 4096 + 3072 + kvh * 128 + dc);
#pragma unroll
            for (int j = 0; j < 8; ++j) tile[r][dc + j] = v[j];
        }
        __syncthreads();
        f16* outb = vtg + (size_t)(bk * 32 + kt) * 8192;
#pragma unroll
        for (int p = 0; p < 4; ++p) {
            int c = p * 256 + tid;
            int kchunk = c >> 7, d = c & 127;
            f16x8 o;
#pragma unroll
            for (int j = 0; j < 8; ++j) o[j] = tile[kchunk * 8 + j][d];
            *(f16x8*)(outb + (size_t)c * 8) = o;
        }
        return;
    }
    // ---- rope ----
    int idx = (bidx - 1024) * 256 + tid;
    const int QTOT = NBATCH * T_SEQ * 16 * 64;  // 8,388,608
    int f, col0, bt;
    bool isQ = idx < QTOT;
    if (isQ) {
        f = idx & 63; int hh = (idx >> 6) & 15; bt = idx >> 10;
        col0 = hh * 128 + f;
    } else {
        int j = idx - QTOT;
        f = j & 63; int hh = (j >> 6) & 7; bt = j >> 9;
        col0 = 2048 + hh * 128 + f;
    }
    int t = bt & (T_SEQ - 1);
    float cs = tab[t * 64 + f], sn = tab[131072 + t * 64 + f], sc = tab[262144 + t * 64 + f];
    float mult = isQ ? sc * 0.08838834764831845f : 1.0f / sc;  // fold 1/sqrt(128) into Q
    size_t p = (size_t)bt * 4096 + col0;
    float x1 = (float)qkv[p], x2 = (float)qkv[p + 64];
    qkv[p]      = (f16)((x1 * cs - x2 * sn) * mult);
    qkv[p + 64] = (f16)((x2 * cs + x1 * sn) * mult);
}

// ---------- 256x256 GEMM, 2-barrier overlapped K-loop (R10 known-good) ----------
template <typename OutT>
__global__ __launch_bounds__(512, 1) void k_gemm256(const f16* __restrict__ A,
                                                    const f16* __restrict__ B,
                                                    OutT* __restrict__ C, int M, int N, int K) {
    extern __shared__ char smem[];
    f16* As = (f16*)smem;            // [2][256][64]
    f16* Bs = (f16*)smem + 32768;    // [2][256][64]
    const int tid = threadIdx.x, lane = tid & 63, w = tid >> 6;
    const int wr4 = w >> 1, wc2 = w & 1;
    const int cq = lane & 15, gq = lane >> 4;
    const int nbx = gridDim.x;                 // n tiles: 16 (GEMM1) or 8 (GEMM2)
    const int bid0 = blockIdx.y * nbx + blockIdx.x;
    const int x = bid0 & 7, idx = bid0 >> 3;   // XCD id, local index
    const int snb = (nbx == 16) ? 3 : 2;       // log2(nbx/2)
    const int mt = (x >> 1) * 8 + (idx >> snb);
    const int nt = (x & 1) * (nbx >> 1) + (idx & ((nbx >> 1) - 1));
    const int m0 = mt * 256, n0 = nt * 256;
    const int KT = K >> 6;

    f32x4 acc[2][2][2][4] = {};
    f16x8 aL[2][2], aH[2][2], bL[4][2], bH[4][2];

    auto stageA = [&](int buf, int half, int t) {
#pragma unroll
        for (int r = 0; r < 2; ++r) {
            int cb = r * 512 + w * 64;
            int c = cb + lane;
            int row = c >> 3, cc = c & 7;
            gld_lds16(A + (size_t)(m0 + half * 128 + row) * K + t * 64 + ((cc ^ (row & 7)) * 8),
                      As + buf * 16384 + half * 8192 + cb * 8);
        }
    };
    auto stageB = [&](int buf, int half, int t) {
#pragma unroll
        for (int r = 0; r < 2; ++r) {
            int cb = r * 512 + w * 64;
            int c = cb + lane;
            int row = c >> 3, cc = c & 7;
            gld_lds16(B + (size_t)(n0 + half * 128 + row) * K + t * 64 + ((cc ^ (row & 7)) * 8),
                      Bs + buf * 16384 + half * 8192 + cb * 8);
        }
    };
    auto rdA = [&](int buf, int qr, f16x8 a[2][2]) {
#pragma unroll
        for (int mi = 0; mi < 2; ++mi)
#pragma unroll
            for (int ks = 0; ks < 2; ++ks) {
                int R = qr * 128 + wr4 * 32 + mi * 16 + cq;
                a[mi][ks] = *(const f16x8*)&As[buf * 16384 + R * 64 + (((ks * 4 + gq) ^ (cq & 7)) * 8)];
            }
    };
    auto rdB = [&](int buf, int qc, f16x8 b[4][2]) {
#pragma unroll
        for (int ni = 0; ni < 4; ++ni)
#pragma unroll
            for (int ks = 0; ks < 2; ++ks) {
                int R = qc * 128 + wc2 * 64 + ni * 16 + cq;
                b[ni][ks] = *(const f16x8*)&Bs[buf * 16384 + R * 64 + (((ks * 4 + gq) ^ (cq & 7)) * 8)];
            }
    };

    // prologue: tile0 all 4 halves + tile1 {Alo,Blo,Bhi}; drain tile0's 8
    stageA(0, 0, 0); stageB(0, 0, 0); stageB(0, 1, 0); stageA(0, 1, 0);
    if (KT > 1) { stageA(1, 0, 1); stageB(1, 0, 1); stageB(1, 1, 1); }
    asm volatile("s_waitcnt vmcnt(6)");
    __builtin_amdgcn_s_barrier();

#pragma unroll 1
    for (int t = 0; t < KT; ++t) {
        const int buf = t & 1;
        rdA(buf, 0, aL); rdB(buf, 0, bL); rdB(buf, 1, bH); rdA(buf, 1, aH);
        __builtin_amdgcn_s_setprio(1);
#pragma unroll
        for (int mi = 0; mi < 2; ++mi)
#pragma unroll
            for (int ni = 0; ni < 4; ++ni)
#pragma unroll
                for (int ks = 0; ks < 2; ++ks)
                    acc[0][0][mi][ni] = __builtin_amdgcn_mfma_f32_16x16x32_f16(aL[mi][ks], bL[ni][ks], acc[0][0][mi][ni], 0, 0, 0);
        __builtin_amdgcn_s_setprio(0);
        if (t + 1 < KT) stageA(buf ^ 1, 1, t + 1);  // S1: Ahi(t+1) -> other buf
        __builtin_amdgcn_s_setprio(1);
#pragma unroll
        for (int mi = 0; mi < 2; ++mi)
#pragma unroll
            for (int ni = 0; ni < 4; ++ni)
#pragma unroll
                for (int ks = 0; ks < 2; ++ks)
                    acc[0][1][mi][ni] = __builtin_amdgcn_mfma_f32_16x16x32_f16(aL[mi][ks], bH[ni][ks], acc[0][1][mi][ni], 0, 0, 0);
        __builtin_amdgcn_s_setprio(0);
        __builtin_amdgcn_s_barrier();
        if (t + 2 < KT) { stageA(buf, 0, t + 2); stageB(buf, 0, t + 2); stageB(buf, 1, t + 2); }  // S2-4
        __builtin_amdgcn_s_setprio(1);
#pragma unroll
        for (int mi = 0; mi < 2; ++mi)
#pragma unroll
            for (int ni = 0; ni < 4; ++ni)
#pragma unroll
                for (int ks = 0; ks < 2; ++ks)
                    acc[1][1][mi][ni] = __builtin_amdgcn_mfma_f32_16x16x32_f16(aH[mi][ks], bH[ni][ks], acc[1][1][mi][ni], 0, 0, 0);
#pragma unroll
        for (int mi = 0; mi < 2; ++mi)
#pragma unroll
            for (int ni = 0; ni < 4; ++ni)
#pragma unroll
                for (int ks = 0; ks < 2; ++ks)
                    acc[1][0][mi][ni] = __builtin_amdgcn_mfma_f32_16x16x32_f16(aH[mi][ks], bL[ni][ks], acc[1][0][mi][ni], 0, 0, 0);
        __builtin_amdgcn_s_setprio(0);
        if (t + 2 < KT)      asm volatile("s_waitcnt vmcnt(6)");
        else                 asm volatile("s_waitcnt vmcnt(0)");
        __builtin_amdgcn_s_barrier();
    }

#pragma unroll
    for (int qr = 0; qr < 2; ++qr)
#pragma unroll
        for (int qc = 0; qc < 2; ++qc)
#pragma unroll
            for (int mi = 0; mi < 2; ++mi)
#pragma unroll
                for (int ni = 0; ni < 4; ++ni)
#pragma unroll
                    for (int i = 0; i < 4; ++i) {
                        int row = m0 + qr * 128 + wr4 * 32 + mi * 16 + gq * 4 + i;
                        int col = n0 + qc * 128 + wc2 * 64 + ni * 16 + cq;
                        C[(size_t)row * N + col] = (OutT)acc[qr][qc][mi][ni][i];
                    }
}

// ---------- causal GQA flash attention, v7: T15 double-pipeline ----------
// 3-buffer K/V ring, counted vmcnt. Per sub-iter: stage(kt+2) -> counted wait ->
// barrier -> QK(kt+1) into St_next (matrix pipe) -> softmax+PV(kt) on St_cur
// (VALU pipe, overlaps) -> barrier. kt-loop unrolled x2 (nkt even) for static
// StA/StB register naming (rule #20).
__global__ __launch_bounds__(512) void k_attn(const f16* __restrict__ qkv,
                                              const f16* __restrict__ vtg,
                                              f16* __restrict__ ao) {
    extern __shared__ f16 asmem[];   // [3][16384]: per buf K 8192 | V 8192
    const int bid0 = blockIdx.x;
    const int bid = (bid0 & 7) * 32 + (bid0 >> 3);  // XCD swizzle (256 = 8x32)
    const int pr = bid & 7, kvh = (bid >> 3) & 7, b = bid >> 6;
    const int bk = b * 8 + kvh;
    const int tid = threadIdx.x, lane = tid & 63, w = tid >> 6;
    const int w4 = w & 3, hg = w >> 2;
    const int h = kvh * 2 + hg;
    const int l31 = lane & 31, hi = lane >> 5;

    const f16* kbase = qkv + (size_t)b * T_SEQ * 4096 + 2048 + kvh * 128;
    const f16* vbase = vtg + (size_t)bk * 32 * 8192;

    auto stage = [&](int buf, int kt) {
        f16* kb_ = asmem + buf * 16384;
        f16* vb_ = kb_ + 8192;
#pragma unroll
        for (int qq = 0; qq < 2; ++qq) {
            int c = w * 128 + qq * 64 + lane;
            int row = c >> 4;
            int ch = (c & 15) ^ (row & 15);
            gld_lds16(kbase + (size_t)(kt * 64 + row) * 4096 + ch * 8, kb_ + (w * 128 + qq * 64) * 8);
        }
#pragma unroll
        for (int qq = 0; qq < 2; ++qq) {
            int c = w * 128 + qq * 64 + lane;
            gld_lds16(vbase + ((size_t)kt * 1024 + c) * 8, vb_ + (w * 128 + qq * 64) * 8);
        }
    };

#pragma unroll 1
    for (int hf = 0; hf < 2; ++hf) {
        const int qt = hf ? pr : (15 - pr);
        const int q0 = qt * 128;
        const int nkt = 2 * qt + 2;  // even, >= 2
        const int qrow = q0 + w4 * 32 + l31;

        f16x8 qf[8];
#pragma unroll
        for (int ds = 0; ds < 8; ++ds)
            qf[ds] = *(const f16x8*)(qkv + (size_t)(b * T_SEQ + qrow) * 4096 + h * 128 + ds * 16 + hi * 8);

        f32x16 Ot[4] = {};
        float mrow = -1e30f, lrow = 0.0f;
        f32x16 SA0 = {}, SA1 = {}, SB0 = {}, SB1 = {};

        // QK(kt) -> S0,S1 (reads Kl[kt%3]); caller zeroes S first
        auto qkc = [&](int kt, f32x16& S0, f32x16& S1) {
            const f16* Kl = asmem + (kt % 3) * 16384;
            __builtin_amdgcn_s_setprio(1);
#pragma unroll
            for (int ds = 0; ds < 8; ++ds) {
                int slot = (((2 * ds + hi) ^ (l31 & 15)) << 3);
                f16x8 k0 = *(const f16x8*)&Kl[l31 * 128 + slot];
                f16x8 k1 = *(const f16x8*)&Kl[(32 + l31) * 128 + slot];
                S0 = __builtin_amdgcn_mfma_f32_32x32x16_f16(k0, qf[ds], S0, 0, 0, 0);
                S1 = __builtin_amdgcn_mfma_f32_32x32x16_f16(k1, qf[ds], S1, 0, 0, 0);
            }
            __builtin_amdgcn_s_setprio(0);
        };

        // mask + online softmax + pack + PV for tile kt on (St0,St1)
        auto proc = [&](int kt, f32x16& St0, f32x16& St1) {
            if (kt == 2 * qt + 1 && w4 < 2) return;  // fully-masked tile
            const f16* Vl = asmem + (kt % 3) * 16384 + 8192;
            if (kt >= 2 * qt) {
                int kbase2 = kt * 64;
#pragma unroll
                for (int r = 0; r < 16; ++r) {
                    int krel = (r & 3) + 8 * (r >> 2) + 4 * hi;
                    if (kbase2 + krel > qrow) St0[r] = -1e30f;
                    if (kbase2 + 32 + krel > qrow) St1[r] = -1e30f;
                }
            }
            float tm[16];
#pragma unroll
            for (int r = 0; r < 16; ++r) tm[r] = fmaxf(St0[r], St1[r]);
#pragma unroll
            for (int d = 8; d >= 1; d >>= 1)
#pragma unroll
                for (int r = 0; r < 8; ++r)
                    if (r < d) tm[r] = fmaxf(tm[r], tm[r + d]);
            float tmax = tm[0];
            float mtile = fmaxf(tmax, __shfl_xor(tmax, 32, 64));

            if (!__all((mtile - mrow) <= 8.0f)) {  // T13 defer-max
                float mnew = fmaxf(mrow, mtile);
                float fs = __expf(mrow - mnew);
                mrow = mnew;
                lrow *= fs;
#pragma unroll
                for (int dblk = 0; dblk < 4; ++dblk)
#pragma unroll
                    for (int e = 0; e < 16; ++e) Ot[dblk][e] *= fs;
            }
#pragma unroll
            for (int r = 0; r < 16; ++r) {
                St0[r] = __expf(St0[r] - mrow);
                St1[r] = __expf(St1[r] - mrow);
            }
            float ts[16];
#pragma unroll
            for (int r = 0; r < 16; ++r) ts[r] = St0[r] + St1[r];
#pragma unroll
            for (int d = 8; d >= 1; d >>= 1)
#pragma unroll
                for (int r = 0; r < 8; ++r)
                    if (r < d) ts[r] += ts[r + d];
            float tsum = ts[0];
            lrow += tsum + __shfl_xor(tsum, 32, 64);

#define PV_P(o, pos) ((o) < 4 ? St0[((o) & 3) * 4 + (pos)] : St1[((o) & 3) * 4 + (pos)])
#pragma unroll
            for (int s = 0; s < 4; ++s) {
                unsigned x1 = pk2(PV_P(2 * s, 0), PV_P(2 * s, 1));
                unsigned x2 = pk2(PV_P(2 * s, 2), PV_P(2 * s, 3));
                unsigned y1 = pk2(PV_P(2 * s + 1, 0), PV_P(2 * s + 1, 1));
                unsigned y2 = pk2(PV_P(2 * s + 1, 2), PV_P(2 * s + 1, 3));
                unsigned sx1 = __shfl_xor(x1, 32, 64);
                unsigned sx2 = __shfl_xor(x2, 32, 64);
                unsigned sy1 = __shfl_xor(y1, 32, 64);
                unsigned sy2 = __shfl_xor(y2, 32, 64);
                u32x4 pw;
                pw[0] = hi ? sy1 : x1;
                pw[1] = hi ? sy2 : x2;
                pw[2] = hi ? y1 : sx1;
                pw[3] = hi ? y2 : sx2;
                f16x8 pa = __builtin_bit_cast(f16x8, pw);
                __builtin_amdgcn_s_setprio(1);
#pragma unroll
                for (int dblk = 0; dblk < 4; ++dblk) {
                    f16x8 vb = *(const f16x8*)&Vl[(((2 * s + hi) << 7) + 32 * dblk + l31) << 3];
                    Ot[dblk] = __builtin_amdgcn_mfma_f32_32x32x16_f16(vb, pa, Ot[dblk], 0, 0, 0);
                }
                __builtin_amdgcn_s_setprio(0);
            }
#undef PV_P
        };

        // prologue: K/V(0) and K/V(1) staged and drained; QK(0) -> A
        stage(0, 0);
        stage(1, 1);
        asm volatile("s_waitcnt vmcnt(0)");
        __builtin_amdgcn_s_barrier();
        qkc(0, SA0, SA1);

#pragma unroll 1
        for (int kt = 0; kt < nkt; kt += 2) {
            // ---- sub-iter even: cur=A (tile kt), next=B (tile kt+1) ----
            if (kt + 2 < nkt) {
                stage((kt + 2) % 3, kt + 2);
                asm volatile("s_waitcnt vmcnt(4)");
            } else {
                asm volatile("s_waitcnt vmcnt(0)");
            }
            __builtin_amdgcn_s_barrier();
            SB0 = f32x16{}; SB1 = f32x16{};
            qkc(kt + 1, SB0, SB1);      // kt+1 < nkt always (nkt even)
            proc(kt, SA0, SA1);
            __builtin_amdgcn_s_barrier();
            // ---- sub-iter odd: cur=B (tile kt+1), next=A (tile kt+2) ----
            if (kt + 3 < nkt) {
                stage((kt + 3) % 3, kt + 3);
                asm volatile("s_waitcnt vmcnt(4)");
            } else {
                asm volatile("s_waitcnt vmcnt(0)");
            }
            __builtin_amdgcn_s_barrier();
            if (kt + 2 < nkt) {
                SA0 = f32x16{}; SA1 = f32x16{};
                qkc(kt + 2, SA0, SA1);
            }
            proc(kt + 1, SB0, SB1);
            __builtin_amdgcn_s_barrier();
        }

        // ---- epilogue ----
        {
            float inv = 1.0f / lrow;
            size_t rowb = (size_t)(b * T_SEQ + qrow) * 2048 + h * 128;
#pragma unroll
            for (int dblk = 0; dblk < 4; ++dblk)
#pragma unroll
                for (int rg = 0; rg < 4; ++rg) {
                    f16x4 o4 = { (f16)(Ot[dblk][rg * 4 + 0] * inv), (f16)(Ot[dblk][rg * 4 + 1] * inv),
                                 (f16)(Ot[dblk][rg * 4 + 2] * inv), (f16)(Ot[dblk][rg * 4 + 3] * inv) };
                    *(f16x4*)(ao + rowb + dblk * 32 + rg * 8 + hi * 4) = o4;
                }
        }
    }
}

extern "C" void kernel_launch(void* const* d_in, const int* in_sizes, int n_in,
                              void* d_out, int out_size, void* d_ws, size_t ws_size,
                              hipStream_t stream) {
    const float* x  = (const float*)d_in[0];
    const float* Wq = (const float*)d_in[1];
    const float* Wk = (const float*)d_in[2];
    const float* Wv = (const float*)d_in[3];
    const float* Wo = (const float*)d_in[4];
    float* out = (float*)d_out;

    // workspace (fp16 elems): xh 16.7M | wqkvT 8.4M | woT 4.2M | qkv 33.5M | tab (f32)
    f16* xh    = (f16*)d_ws;
    f16* wqkvT = xh + (size_t)16777216;
    f16* woT   = wqkvT + (size_t)8388608;
    f16* qkv   = woT + (size_t)4194304;
    float* tab = (float*)(qkv + (size_t)33554432);
    f16* ao  = xh;     // alias: xh dead after GEMM1
    f16* vtg = wqkvT;  // alias: wqkvT dead after GEMM1 (8.4M f16 = exact fit)

    hipFuncSetAttribute(reinterpret_cast<const void*>(&k_gemm256<f16>),
                        hipFuncAttributeMaxDynamicSharedMemorySize, 131072);
    hipFuncSetAttribute(reinterpret_cast<const void*>(&k_gemm256<float>),
                        hipFuncAttributeMaxDynamicSharedMemorySize, 131072);
    hipFuncSetAttribute(reinterpret_cast<const void*>(&k_attn),
                        hipFuncAttributeMaxDynamicSharedMemorySize, 98304);

    k_prep<<<29184, 256, 0, stream>>>(x, Wq, Wk, Wv, Wo, xh, wqkvT, woT, tab);
    // QKV projection: qkv[8192][4096]
    k_gemm256<f16><<<dim3(16, 32), 512, 131072, stream>>>(xh, wqkvT, qkv, 8192, 4096, 2048);
    // fused vtrans + rope (disjoint qkv regions)
    k_post<<<50176, 256, 0, stream>>>(qkv, vtg, tab);
    k_attn<<<256, 512, 98304, stream>>>(qkv, vtg, ao);
    // output projection -> fp32
    k_gemm256<float><<<dim3(8, 32), 512, 131072, stream>>>(ao, woT, out, 8192, 2048, 2048);
}